// Round 1
// baseline (330.486 us; speedup 1.0000x reference)
//
#include <hip/hip_runtime.h>

typedef unsigned short u16;
typedef __attribute__((ext_vector_type(4))) float f32x4;
typedef __attribute__((ext_vector_type(8))) short bf16x8;
typedef __attribute__((ext_vector_type(8))) u16 u16x8;
typedef __attribute__((ext_vector_type(4))) u16 u16x4;

#define DEVI __device__ __forceinline__

constexpr int C_ = 512, S_ = 32768, L_ = 256, CTX_ = 768;

DEVI u16 f2b(float f) {  // fp32 -> bf16 RNE
    union { float f; unsigned u; } x; x.f = f;
    unsigned r = x.u + 0x7fffu + ((x.u >> 16) & 1u);
    return (u16)(r >> 16);
}

DEVI f32x4 mfma16(bf16x8 a, bf16x8 b, f32x4 c) {
    return __builtin_amdgcn_mfma_f32_16x16x32_bf16(a, b, c, 0, 0, 0);
}

DEVI void gload16(const void* g, void* l) {
    __builtin_amdgcn_global_load_lds(
        (const __attribute__((address_space(1))) void*)g,
        (__attribute__((address_space(3))) void*)l, 16, 0, 0);
}

// ---------------------------------------------------------------- weights cvt
__global__ __launch_bounds__(256) void cvt_w(
    const float* __restrict__ a0, const float* __restrict__ a1,
    const float* __restrict__ a2, const float* __restrict__ a3,
    u16* __restrict__ o0, u16* __restrict__ o1,
    u16* __restrict__ o2, u16* __restrict__ o3)
{
    int which = blockIdx.y;
    const float* src = which == 0 ? a0 : which == 1 ? a1 : which == 2 ? a2 : a3;
    u16* dst = which == 0 ? o0 : which == 1 ? o1 : which == 2 ? o2 : o3;
    int n4 = (which == 1 || which == 2) ? (512 * 768 / 4) : (512 * 512 / 4);
    int i = blockIdx.x * 256 + threadIdx.x;
    if (i < n4) {
        float4 v = ((const float4*)src)[i];
        u16x4 o; o[0] = f2b(v.x); o[1] = f2b(v.y); o[2] = f2b(v.z); o[3] = f2b(v.w);
        ((u16x4*)dst)[i] = o;
    }
}

// ---------------------------------------------------------------- GN stats
__global__ __launch_bounds__(256) void gn_partial(const float* __restrict__ x,
                                                  float* __restrict__ part)
{
    const int bg = blockIdx.y, blk = blockIdx.x, tid = threadIdx.x;
    const float* base = x + (size_t)bg * 64 * S_ + (size_t)blk * 512;
    float s1 = 0.f, s2 = 0.f;
    for (int c = 0; c < 64; ++c) {
        const float* row = base + (size_t)c * S_;
        float v0 = row[tid], v1 = row[tid + 256];
        s1 += v0 + v1; s2 += v0 * v0 + v1 * v1;
    }
    for (int m = 1; m < 64; m <<= 1) { s1 += __shfl_xor(s1, m); s2 += __shfl_xor(s2, m); }
    __shared__ float a1[4], a2[4];
    int w = tid >> 6, lane = tid & 63;
    if (lane == 0) { a1[w] = s1; a2[w] = s2; }
    __syncthreads();
    if (tid == 0) {
        part[(bg * 64 + blk) * 2 + 0] = a1[0] + a1[1] + a1[2] + a1[3];
        part[(bg * 64 + blk) * 2 + 1] = a2[0] + a2[1] + a2[2] + a2[3];
    }
}

__global__ __launch_bounds__(64) void gn_final(const float* __restrict__ part,
                                               float* __restrict__ stats)
{
    int bg = blockIdx.x, tid = threadIdx.x;
    float s1 = part[(bg * 64 + tid) * 2], s2 = part[(bg * 64 + tid) * 2 + 1];
    for (int m = 1; m < 64; m <<= 1) { s1 += __shfl_xor(s1, m); s2 += __shfl_xor(s2, m); }
    if (tid == 0) {
        const float invN = 1.0f / (64.0f * (float)S_);
        float mu = s1 * invN, var = s2 * invN - mu * mu;
        stats[bg * 2] = mu;
        stats[bg * 2 + 1] = rsqrtf(var + 1e-5f);
    }
}

// ------------------------------------------- GN apply + transpose to (b,s,c) bf16
__global__ __launch_bounds__(256) void gn_apply(
    const float* __restrict__ x, const float* __restrict__ stats,
    const float* __restrict__ gw, const float* __restrict__ gb,
    u16* __restrict__ ht)
{
    __shared__ float tile[64][65];
    const int tid = threadIdx.x, sl = tid & 63, c4 = tid >> 6;
    const int s0 = blockIdx.x * 64, c0 = blockIdx.y * 64, b = blockIdx.z;
    const int bg = b * 8 + (c0 >> 6);
    const float mu = stats[bg * 2], rstd = stats[bg * 2 + 1];
#pragma unroll
    for (int i = 0; i < 16; ++i) {
        int cl = c4 * 16 + i;
        float wv = gw[c0 + cl], bv = gb[c0 + cl];
        float v = x[((size_t)(b * C_ + c0 + cl)) * S_ + s0 + sl];
        tile[sl][cl] = (v - mu) * rstd * wv + bv;
    }
    __syncthreads();
#pragma unroll
    for (int i = 0; i < 16; ++i) {
        int so = c4 * 16 + i;
        ht[((size_t)(b * S_ + s0 + so)) * C_ + c0 + sl] = f2b(tile[so][sl]);
    }
}

// ---------------------------------------------------------------- LayerNorm(ctx)
__global__ __launch_bounds__(256) void ln_ctx(
    const float* __restrict__ ctx, const float* __restrict__ lw,
    const float* __restrict__ lb, u16* __restrict__ cn)
{
    const int row = blockIdx.x, tid = threadIdx.x;
    const float* p = ctx + (size_t)row * CTX_;
    float v0 = p[tid], v1 = p[tid + 256], v2 = p[tid + 512];
    float s1 = v0 + v1 + v2, s2 = v0 * v0 + v1 * v1 + v2 * v2;
    for (int m = 1; m < 64; m <<= 1) { s1 += __shfl_xor(s1, m); s2 += __shfl_xor(s2, m); }
    __shared__ float a1[4], a2[4];
    int w = tid >> 6, lane = tid & 63;
    if (lane == 0) { a1[w] = s1; a2[w] = s2; }
    __syncthreads();
    s1 = a1[0] + a1[1] + a1[2] + a1[3];
    s2 = a2[0] + a2[1] + a2[2] + a2[3];
    const float invN = 1.0f / 768.0f;
    float mu = s1 * invN, rstd = rsqrtf(s2 * invN - mu * mu + 1e-5f);
    u16* o = cn + (size_t)row * CTX_;
    o[tid]       = f2b((v0 - mu) * rstd * lw[tid]       + lb[tid]);
    o[tid + 256] = f2b((v1 - mu) * rstd * lw[tid + 256] + lb[tid + 256]);
    o[tid + 512] = f2b((v2 - mu) * rstd * lw[tid + 512] + lb[tid + 512]);
}

// ---------------------------------------------------------------- NT-GEMM
// C[m][n] = sum_k A[m*K+k] * B[n*K+k]   (both operands K-contiguous bf16)
// MODE 0: bf16 out[m*ldo+n] = (acc + bias[n]) * scale
// MODE 1: bf16 v-scatter  out[((m/256)*512 + n)*256 + (m%256)] = acc + bias[n]
// MODE 2: f32  out[m*ldo+n] = acc + bias[m] + resid[m*ldo+n]
template <int MODE>
__global__ __launch_bounds__(256, 2) void gemm_nt(
    const u16* __restrict__ A, const u16* __restrict__ Bp,
    const float* __restrict__ bias, void* __restrict__ outp,
    const float* __restrict__ resid, int K, int ldo,
    size_t aStride, size_t bStride, size_t oStride, float scale)
{
    __shared__ __align__(16) u16 lA[128 * 32];
    __shared__ __align__(16) u16 lB[128 * 32];
    const int tid = threadIdx.x;
    const int w = tid >> 6, lane = tid & 63;
    const int g = lane >> 4, r = lane & 15;
    const int m0 = blockIdx.x * 128, n0 = blockIdx.y * 128;
    const int z = blockIdx.z;
    A += (size_t)z * aStride;
    Bp += (size_t)z * bStride;

    const int srow = w * 32 + (lane >> 2);   // staging row (j adds 16)
    const int skc = (lane & 3) * 8;          // staging k offset (elements)
    const int wr = w >> 1, wc = w & 1;

    f32x4 acc[4][4];
#pragma unroll
    for (int m = 0; m < 4; ++m)
#pragma unroll
        for (int n = 0; n < 4; ++n) acc[m][n] = f32x4{0.f, 0.f, 0.f, 0.f};

    for (int kt = 0; kt < K; kt += 32) {
        __syncthreads();
#pragma unroll
        for (int j = 0; j < 2; ++j) {
            int row = srow + j * 16;
            gload16(A + (size_t)(m0 + row) * K + kt + skc, &lA[(w * 32 + j * 16) * 32]);
            gload16(Bp + (size_t)(n0 + row) * K + kt + skc, &lB[(w * 32 + j * 16) * 32]);
        }
        __syncthreads();
        bf16x8 af[4], bf_[4];
#pragma unroll
        for (int m = 0; m < 4; ++m) af[m] = *(const bf16x8*)&lA[(wr * 64 + m * 16 + r) * 32 + g * 8];
#pragma unroll
        for (int n = 0; n < 4; ++n) bf_[n] = *(const bf16x8*)&lB[(wc * 64 + n * 16 + r) * 32 + g * 8];
#pragma unroll
        for (int m = 0; m < 4; ++m)
#pragma unroll
            for (int n = 0; n < 4; ++n)
                acc[m][n] = mfma16(af[m], bf_[n], acc[m][n]);
    }

    if constexpr (MODE == 0) {
        u16* ob = (u16*)outp + (size_t)z * oStride;
#pragma unroll
        for (int n = 0; n < 4; ++n) {
            int gn = n0 + wc * 64 + n * 16 + r;
            float bn = bias[gn] * scale;
#pragma unroll
            for (int m = 0; m < 4; ++m) {
                int gm = m0 + wr * 64 + m * 16 + g * 4;
#pragma unroll
                for (int i = 0; i < 4; ++i)
                    ob[(size_t)(gm + i) * ldo + gn] = f2b(acc[m][n][i] * scale + bn);
            }
        }
    } else if constexpr (MODE == 1) {
        u16* ob = (u16*)outp;
#pragma unroll
        for (int n = 0; n < 4; ++n) {
            int gn = n0 + wc * 64 + n * 16 + r;
            float bn = bias[gn];
#pragma unroll
            for (int m = 0; m < 4; ++m) {
                int gm = m0 + wr * 64 + m * 16 + g * 4;
                int bb = gm >> 8, l = gm & 255;
                u16x4 pk;
#pragma unroll
                for (int i = 0; i < 4; ++i) pk[i] = f2b(acc[m][n][i] + bn);
                *(u16x4*)&ob[((size_t)(bb * 512 + gn)) * 256 + l] = pk;
            }
        }
    } else {
        float* of = (float*)outp + (size_t)z * oStride;
        const float* rs = resid + (size_t)z * oStride;
#pragma unroll
        for (int m = 0; m < 4; ++m) {
            int gm = m0 + wr * 64 + m * 16 + g * 4;
#pragma unroll
            for (int i = 0; i < 4; ++i) {
                float bm = bias[gm + i];
#pragma unroll
                for (int n = 0; n < 4; ++n) {
                    int gn = n0 + wc * 64 + n * 16 + r;
                    size_t idx = (size_t)(gm + i) * ldo + gn;
                    of[idx] = acc[m][n][i] + bm + rs[idx];
                }
            }
        }
    }
}

// ---------------------------------------------------------------- attention
// grid: (S/128, B*NH). block 256 (4 waves, 32 s-rows each).
// LDS 64KB: [0,32KB) K (256l x 64e, swizzled) -> later P (per-wave 32s x 128l halves)
//           [32KB,64KB) V as (64e x 256l, swizzled)
__global__ __launch_bounds__(256, 2) void attn_kernel(
    const u16* __restrict__ q, const u16* __restrict__ kk,
    const u16* __restrict__ vv, u16* __restrict__ ao)
{
    __shared__ __align__(16) u16 sm[32768];
    const int tid = threadIdx.x;
    const int w = tid >> 6, lane = tid & 63;
    const int g = lane >> 4, r = lane & 15;
    const int bh = blockIdx.y, b = bh >> 3, h = bh & 7;
    const int s0 = blockIdx.x * 128;

    {   // stage K (b,l,h*64+e) rows -> sm[l*64 + swz]
        const u16* kbase = kk + ((size_t)b * L_) * C_ + h * 64;
#pragma unroll
        for (int j = 0; j < 8; ++j) {
            int idx = j * 256 + tid;
            int l = idx >> 3, ch = idx & 7;
            u16x8 val = *(const u16x8*)(kbase + (size_t)l * C_ + ch * 8);
            *(u16x8*)&sm[l * 64 + ((ch ^ (l & 7)) << 3)] = val;
        }
        // stage V (b,h,e,l) rows -> sm[16384 + e*256 + swz]
        const u16* vbase = vv + ((size_t)bh * 64) * 256;
#pragma unroll
        for (int j = 0; j < 8; ++j) {
            int idx = j * 256 + tid;
            int e = idx >> 5, ch = idx & 31;
            u16x8 val = *(const u16x8*)(vbase + (size_t)e * 256 + ch * 8);
            *(u16x8*)&sm[16384 + e * 256 + ((ch ^ (e & 7)) << 3)] = val;
        }
    }
    __syncthreads();

    // Q fragments straight from global (read-once)
    const int sw = s0 + w * 32;
    bf16x8 qf[2][2];
#pragma unroll
    for (int m = 0; m < 2; ++m)
#pragma unroll
        for (int kt = 0; kt < 2; ++kt)
            qf[m][kt] = *(const bf16x8*)(q + ((size_t)(b * S_ + sw + m * 16 + r)) * C_
                                         + h * 64 + kt * 32 + g * 8);

    // QK^T: scores[s 32][l 256]
    f32x4 accs[2][16];
#pragma unroll
    for (int m = 0; m < 2; ++m)
#pragma unroll
        for (int n = 0; n < 16; ++n) accs[m][n] = f32x4{0.f, 0.f, 0.f, 0.f};
#pragma unroll
    for (int n = 0; n < 16; ++n) {
#pragma unroll
        for (int kt = 0; kt < 2; ++kt) {
            int c = kt * 4 + g;  // e-chunk index
            bf16x8 kf = *(const bf16x8*)&sm[(n * 16 + r) * 64 + ((c ^ (r & 7)) << 3)];
#pragma unroll
            for (int m = 0; m < 2; ++m) accs[m][n] = mfma16(qf[m][kt], kf, accs[m][n]);
        }
    }

    // wave-parallel softmax over l (rows live across 16-lane groups)
    float mx[2][4], inv[2][4];
#pragma unroll
    for (int m = 0; m < 2; ++m)
#pragma unroll
        for (int i = 0; i < 4; ++i) {
            float v = accs[m][0][i];
#pragma unroll
            for (int n = 1; n < 16; ++n) v = fmaxf(v, accs[m][n][i]);
#pragma unroll
            for (int msk = 1; msk < 16; msk <<= 1) v = fmaxf(v, __shfl_xor(v, msk));
            mx[m][i] = v;
        }
#pragma unroll
    for (int m = 0; m < 2; ++m)
#pragma unroll
        for (int i = 0; i < 4; ++i) {
            float sum = 0.f;
#pragma unroll
            for (int n = 0; n < 16; ++n) {
                float e = __expf(accs[m][n][i] - mx[m][i]);
                accs[m][n][i] = e; sum += e;
            }
#pragma unroll
            for (int msk = 1; msk < 16; msk <<= 1) sum += __shfl_xor(sum, msk);
            inv[m][i] = 1.0f / sum;
        }

    __syncthreads();  // everyone done reading K; reuse its LDS for P

    // PV in two half-L chunks through per-wave P buffer (8 KB each)
    f32x4 acco[2][4];
#pragma unroll
    for (int m = 0; m < 2; ++m)
#pragma unroll
        for (int n = 0; n < 4; ++n) acco[m][n] = f32x4{0.f, 0.f, 0.f, 0.f};

#pragma unroll
    for (int half = 0; half < 2; ++half) {
#pragma unroll
        for (int m = 0; m < 2; ++m)
#pragma unroll
            for (int n8 = 0; n8 < 8; ++n8) {
                int n = half * 8 + n8;
                int lh = n8 * 16 + r;
#pragma unroll
                for (int i = 0; i < 4; ++i) {
                    int sl = m * 16 + g * 4 + i;
                    float p = accs[m][n][i] * inv[m][i];
                    sm[w * 4096 + sl * 128 + (((lh >> 3) ^ (sl & 7)) << 3) + (lh & 7)] = f2b(p);
                }
            }
#pragma unroll
        for (int kt = 0; kt < 4; ++kt) {
            int l0 = kt * 32 + g * 8;       // within half
            int lg = half * 128 + l0;       // global l
            bf16x8 pf[2], vf[4];
#pragma unroll
            for (int m = 0; m < 2; ++m) {
                int sl = m * 16 + r;
                pf[m] = *(const bf16x8*)&sm[w * 4096 + sl * 128 + (((l0 >> 3) ^ (r & 7)) << 3)];
            }
#pragma unroll
            for (int n = 0; n < 4; ++n) {
                int e = n * 16 + r;
                vf[n] = *(const bf16x8*)&sm[16384 + e * 256 + (((lg >> 3) ^ (r & 7)) << 3)];
            }
#pragma unroll
            for (int m = 0; m < 2; ++m)
#pragma unroll
                for (int n = 0; n < 4; ++n)
                    acco[m][n] = mfma16(pf[m], vf[n], acco[m][n]);
        }
    }

    // write attention output as (b, s, c=h*64+e) bf16
#pragma unroll
    for (int m = 0; m < 2; ++m)
#pragma unroll
        for (int n = 0; n < 4; ++n)
#pragma unroll
            for (int i = 0; i < 4; ++i) {
                int s = sw + m * 16 + g * 4 + i;
                int e = n * 16 + r;
                ao[((size_t)(b * S_ + s)) * C_ + h * 64 + e] = f2b(acco[m][n][i]);
            }
}

// ---------------------------------------------------------------- launch
extern "C" void kernel_launch(void* const* d_in, const int* in_sizes, int n_in,
                              void* d_out, int out_size, void* d_ws, size_t ws_size,
                              hipStream_t stream)
{
    (void)in_sizes; (void)n_in; (void)out_size; (void)ws_size;
    const float* x    = (const float*)d_in[0];
    const float* ctx  = (const float*)d_in[1];
    const float* gn_w = (const float*)d_in[2];
    const float* gn_b = (const float*)d_in[3];
    const float* ln_w = (const float*)d_in[4];
    const float* ln_b = (const float*)d_in[5];
    const float* q_w  = (const float*)d_in[6];
    const float* q_b  = (const float*)d_in[7];
    const float* k_w  = (const float*)d_in[8];
    const float* k_b  = (const float*)d_in[9];
    const float* v_w  = (const float*)d_in[10];
    const float* v_b  = (const float*)d_in[11];
    const float* p_w  = (const float*)d_in[12];
    const float* p_b  = (const float*)d_in[13];
    float* out = (float*)d_out;

    char* ws = (char*)d_ws;
    constexpr size_t WS_WQ   = 0;
    constexpr size_t WS_WK   = WS_WQ + (size_t)512 * 512 * 2;
    constexpr size_t WS_WV   = WS_WK + (size_t)512 * 768 * 2;
    constexpr size_t WS_WP   = WS_WV + (size_t)512 * 768 * 2;
    constexpr size_t WS_PART = WS_WP + (size_t)512 * 512 * 2;
    constexpr size_t WS_STAT = WS_PART + (size_t)16 * 64 * 2 * 4;
    constexpr size_t WS_CTXN = WS_STAT + 256;
    constexpr size_t WS_K    = WS_CTXN + (size_t)512 * 768 * 2;
    constexpr size_t WS_V    = WS_K + (size_t)2 * 8 * 256 * 64 * 2;
    constexpr size_t WS_Q    = WS_V + (size_t)2 * 8 * 256 * 64 * 2;
    constexpr size_t WS_H    = WS_Q + (size_t)2 * 32768 * 512 * 2;

    u16* wq = (u16*)(ws + WS_WQ);
    u16* wk = (u16*)(ws + WS_WK);
    u16* wv = (u16*)(ws + WS_WV);
    u16* wp = (u16*)(ws + WS_WP);
    float* part  = (float*)(ws + WS_PART);
    float* stats = (float*)(ws + WS_STAT);
    u16* ctxn = (u16*)(ws + WS_CTXN);
    u16* kt   = (u16*)(ws + WS_K);
    u16* vt   = (u16*)(ws + WS_V);
    u16* qt   = (u16*)(ws + WS_Q);
    u16* ht   = (u16*)(ws + WS_H);
    u16* ao   = ht;  // h dead after Q-GEMM; reuse for attention output

    const size_t bsc = (size_t)S_ * C_;  // per-batch (s,c)/(c,s) stride

    cvt_w<<<dim3(384, 4), 256, 0, stream>>>(q_w, k_w, v_w, p_w, wq, wk, wv, wp);
    gn_partial<<<dim3(64, 16), 256, 0, stream>>>(x, part);
    gn_final<<<16, 64, 0, stream>>>(part, stats);
    gn_apply<<<dim3(512, 8, 2), 256, 0, stream>>>(x, stats, gn_w, gn_b, ht);
    ln_ctx<<<512, 256, 0, stream>>>(ctx, ln_w, ln_b, ctxn);
    // Q = h . Wq^T  (scale folded), out (b,s,o) bf16
    gemm_nt<0><<<dim3(256, 4, 2), 256, 0, stream>>>(ht, wq, q_b, qt, nullptr,
                                                    512, 512, bsc, 0, bsc, 0.125f);
    // K = ctxn . Wk^T, out (b*l, o) bf16
    gemm_nt<0><<<dim3(4, 4, 1), 256, 0, stream>>>(ctxn, wk, k_b, kt, nullptr,
                                                  768, 512, 0, 0, 0, 1.0f);
    // V = ctxn . Wv^T, scattered to (b,h,e,l) bf16
    gemm_nt<1><<<dim3(4, 4, 1), 256, 0, stream>>>(ctxn, wv, v_b, vt, nullptr,
                                                  768, 0, 0, 0, 0, 1.0f);
    attn_kernel<<<dim3(256, 16), 256, 0, stream>>>(qt, kt, vt, ao);
    // out = Wp . ao^T + bias + x  (fp32, (b,c,s))
    gemm_nt<2><<<dim3(4, 256, 2), 256, 0, stream>>>(wp, ao, p_b, out, x,
                                                    512, S_, 0, bsc, bsc, 1.0f);
}

// Round 2
// 307.823 us; speedup vs baseline: 1.0736x; 1.0736x over previous
//
#include <hip/hip_runtime.h>

typedef unsigned short u16;
typedef unsigned int u32;
typedef __attribute__((ext_vector_type(4))) float f32x4;
typedef __attribute__((ext_vector_type(8))) short bf16x8;
typedef __attribute__((ext_vector_type(8))) u16 u16x8;
typedef __attribute__((ext_vector_type(4))) u16 u16x4;
typedef __attribute__((ext_vector_type(4))) u32 u32x4;

#define DEVI __device__ __forceinline__

constexpr int C_ = 512, S_ = 32768, L_ = 256, CTX_ = 768;

DEVI u16 f2b(float f) {  // fp32 -> bf16 RNE
    union { float f; unsigned u; } x; x.f = f;
    unsigned r = x.u + 0x7fffu + ((x.u >> 16) & 1u);
    return (u16)(r >> 16);
}

DEVI f32x4 mfma16(bf16x8 a, bf16x8 b, f32x4 c) {
    return __builtin_amdgcn_mfma_f32_16x16x32_bf16(a, b, c, 0, 0, 0);
}

DEVI void gload16(const void* g, void* l) {
    __builtin_amdgcn_global_load_lds(
        (const __attribute__((address_space(1))) void*)g,
        (__attribute__((address_space(3))) void*)l, 16, 0, 0);
}

DEVI u32 cvtpk(float lo, float hi) {  // {hi_bf16, lo_bf16}
    u32 d;
    asm("v_cvt_pk_bf16_f32 %0, %1, %2" : "=v"(d) : "v"(lo), "v"(hi));
    return d;
}
DEVI void pl32(u32& a, u32& b) {  // a=[a_lo|b_lo], b=[a_hi|b_hi]
    asm volatile("v_permlane32_swap_b32 %0, %1" : "+v"(a), "+v"(b));
}
DEVI void pl16(u32& a, u32& b) {  // swap odd16 of a with even16 of b per half
    asm volatile("v_permlane16_swap_b32 %0, %1" : "+v"(a), "+v"(b));
}

// ---------------------------------------------------------------- weights cvt
__global__ __launch_bounds__(256) void cvt_w(
    const float* __restrict__ a0, const float* __restrict__ a1,
    const float* __restrict__ a2, const float* __restrict__ a3,
    u16* __restrict__ o0, u16* __restrict__ o1,
    u16* __restrict__ o2, u16* __restrict__ o3)
{
    int which = blockIdx.y;
    const float* src = which == 0 ? a0 : which == 1 ? a1 : which == 2 ? a2 : a3;
    u16* dst = which == 0 ? o0 : which == 1 ? o1 : which == 2 ? o2 : o3;
    int n4 = (which == 1 || which == 2) ? (512 * 768 / 4) : (512 * 512 / 4);
    int i = blockIdx.x * 256 + threadIdx.x;
    if (i < n4) {
        float4 v = ((const float4*)src)[i];
        u16x4 o; o[0] = f2b(v.x); o[1] = f2b(v.y); o[2] = f2b(v.z); o[3] = f2b(v.w);
        ((u16x4*)dst)[i] = o;
    }
}

// ---------------------------------------------------------------- GN stats
__global__ __launch_bounds__(256) void gn_partial(const float* __restrict__ x,
                                                  float* __restrict__ part)
{
    const int bg = blockIdx.y, blk = blockIdx.x, tid = threadIdx.x;
    const float* base = x + (size_t)bg * 64 * S_ + (size_t)blk * 512;
    float s1 = 0.f, s2 = 0.f;
    for (int c = 0; c < 64; ++c) {
        const float* row = base + (size_t)c * S_;
        float v0 = row[tid], v1 = row[tid + 256];
        s1 += v0 + v1; s2 += v0 * v0 + v1 * v1;
    }
    for (int m = 1; m < 64; m <<= 1) { s1 += __shfl_xor(s1, m); s2 += __shfl_xor(s2, m); }
    __shared__ float a1[4], a2[4];
    int w = tid >> 6, lane = tid & 63;
    if (lane == 0) { a1[w] = s1; a2[w] = s2; }
    __syncthreads();
    if (tid == 0) {
        part[(bg * 64 + blk) * 2 + 0] = a1[0] + a1[1] + a1[2] + a1[3];
        part[(bg * 64 + blk) * 2 + 1] = a2[0] + a2[1] + a2[2] + a2[3];
    }
}

__global__ __launch_bounds__(64) void gn_final(const float* __restrict__ part,
                                               float* __restrict__ stats)
{
    int bg = blockIdx.x, tid = threadIdx.x;
    float s1 = part[(bg * 64 + tid) * 2], s2 = part[(bg * 64 + tid) * 2 + 1];
    for (int m = 1; m < 64; m <<= 1) { s1 += __shfl_xor(s1, m); s2 += __shfl_xor(s2, m); }
    if (tid == 0) {
        const float invN = 1.0f / (64.0f * (float)S_);
        float mu = s1 * invN, var = s2 * invN - mu * mu;
        stats[bg * 2] = mu;
        stats[bg * 2 + 1] = rsqrtf(var + 1e-5f);
    }
}

// ------------------------------------------- GN apply + transpose to (b,s,c) bf16
__global__ __launch_bounds__(256) void gn_apply(
    const float* __restrict__ x, const float* __restrict__ stats,
    const float* __restrict__ gw, const float* __restrict__ gb,
    u16* __restrict__ ht)
{
    __shared__ float tile[64][65];
    const int tid = threadIdx.x, sl = tid & 63, c4 = tid >> 6;
    const int s0 = blockIdx.x * 64, c0 = blockIdx.y * 64, b = blockIdx.z;
    const int bg = b * 8 + (c0 >> 6);
    const float mu = stats[bg * 2], rstd = stats[bg * 2 + 1];
#pragma unroll
    for (int i = 0; i < 16; ++i) {
        int cl = c4 * 16 + i;
        float wv = gw[c0 + cl], bv = gb[c0 + cl];
        float v = x[((size_t)(b * C_ + c0 + cl)) * S_ + s0 + sl];
        tile[sl][cl] = (v - mu) * rstd * wv + bv;
    }
    __syncthreads();
#pragma unroll
    for (int i = 0; i < 16; ++i) {
        int so = c4 * 16 + i;
        ht[((size_t)(b * S_ + s0 + so)) * C_ + c0 + sl] = f2b(tile[so][sl]);
    }
}

// ---------------------------------------------------------------- LayerNorm(ctx)
__global__ __launch_bounds__(256) void ln_ctx(
    const float* __restrict__ ctx, const float* __restrict__ lw,
    const float* __restrict__ lb, u16* __restrict__ cn)
{
    const int row = blockIdx.x, tid = threadIdx.x;
    const float* p = ctx + (size_t)row * CTX_;
    float v0 = p[tid], v1 = p[tid + 256], v2 = p[tid + 512];
    float s1 = v0 + v1 + v2, s2 = v0 * v0 + v1 * v1 + v2 * v2;
    for (int m = 1; m < 64; m <<= 1) { s1 += __shfl_xor(s1, m); s2 += __shfl_xor(s2, m); }
    __shared__ float a1[4], a2[4];
    int w = tid >> 6, lane = tid & 63;
    if (lane == 0) { a1[w] = s1; a2[w] = s2; }
    __syncthreads();
    s1 = a1[0] + a1[1] + a1[2] + a1[3];
    s2 = a2[0] + a2[1] + a2[2] + a2[3];
    const float invN = 1.0f / 768.0f;
    float mu = s1 * invN, rstd = rsqrtf(s2 * invN - mu * mu + 1e-5f);
    u16* o = cn + (size_t)row * CTX_;
    o[tid]       = f2b((v0 - mu) * rstd * lw[tid]       + lb[tid]);
    o[tid + 256] = f2b((v1 - mu) * rstd * lw[tid + 256] + lb[tid + 256]);
    o[tid + 512] = f2b((v2 - mu) * rstd * lw[tid + 512] + lb[tid + 512]);
}

// ---------------------------------------------------------------- NT-GEMM
// C[m][n] = sum_k A[m*K+k] * B[n*K+k]   (both operands K-contiguous bf16)
// MODE 0: bf16 out[m*ldo+n] = (acc + bias[n]) * scale
// MODE 1: bf16 v-scatter  out[((m/256)*512 + n)*256 + (m%256)] = acc + bias[n]
// MODE 2: f32  out[m*ldo+n] = acc + bias[m] + resid[m*ldo+n]
template <int MODE>
__global__ __launch_bounds__(256, 2) void gemm_nt(
    const u16* __restrict__ A, const u16* __restrict__ Bp,
    const float* __restrict__ bias, void* __restrict__ outp,
    const float* __restrict__ resid, int K, int ldo,
    size_t aStride, size_t bStride, size_t oStride, float scale)
{
    __shared__ __align__(16) u16 lA[128 * 32];
    __shared__ __align__(16) u16 lB[128 * 32];
    const int tid = threadIdx.x;
    const int w = tid >> 6, lane = tid & 63;
    const int g = lane >> 4, r = lane & 15;
    const int m0 = blockIdx.x * 128, n0 = blockIdx.y * 128;
    const int z = blockIdx.z;
    A += (size_t)z * aStride;
    Bp += (size_t)z * bStride;

    const int srow = w * 32 + (lane >> 2);   // staging row (j adds 16)
    const int skc = (lane & 3) * 8;          // staging k offset (elements)
    const int wr = w >> 1, wc = w & 1;

    f32x4 acc[4][4];
#pragma unroll
    for (int m = 0; m < 4; ++m)
#pragma unroll
        for (int n = 0; n < 4; ++n) acc[m][n] = f32x4{0.f, 0.f, 0.f, 0.f};

    for (int kt = 0; kt < K; kt += 32) {
        __syncthreads();
#pragma unroll
        for (int j = 0; j < 2; ++j) {
            int row = srow + j * 16;
            gload16(A + (size_t)(m0 + row) * K + kt + skc, &lA[(w * 32 + j * 16) * 32]);
            gload16(Bp + (size_t)(n0 + row) * K + kt + skc, &lB[(w * 32 + j * 16) * 32]);
        }
        __syncthreads();
        bf16x8 af[4], bf_[4];
#pragma unroll
        for (int m = 0; m < 4; ++m) af[m] = *(const bf16x8*)&lA[(wr * 64 + m * 16 + r) * 32 + g * 8];
#pragma unroll
        for (int n = 0; n < 4; ++n) bf_[n] = *(const bf16x8*)&lB[(wc * 64 + n * 16 + r) * 32 + g * 8];
#pragma unroll
        for (int m = 0; m < 4; ++m)
#pragma unroll
            for (int n = 0; n < 4; ++n)
                acc[m][n] = mfma16(af[m], bf_[n], acc[m][n]);
    }

    if constexpr (MODE == 0) {
        u16* ob = (u16*)outp + (size_t)z * oStride;
#pragma unroll
        for (int n = 0; n < 4; ++n) {
            int gn = n0 + wc * 64 + n * 16 + r;
            float bn = bias[gn] * scale;
#pragma unroll
            for (int m = 0; m < 4; ++m) {
                int gm = m0 + wr * 64 + m * 16 + g * 4;
#pragma unroll
                for (int i = 0; i < 4; ++i)
                    ob[(size_t)(gm + i) * ldo + gn] = f2b(acc[m][n][i] * scale + bn);
            }
        }
    } else if constexpr (MODE == 1) {
        u16* ob = (u16*)outp;
#pragma unroll
        for (int n = 0; n < 4; ++n) {
            int gn = n0 + wc * 64 + n * 16 + r;
            float bn = bias[gn];
#pragma unroll
            for (int m = 0; m < 4; ++m) {
                int gm = m0 + wr * 64 + m * 16 + g * 4;
                int bb = gm >> 8, l = gm & 255;
                u16x4 pk;
#pragma unroll
                for (int i = 0; i < 4; ++i) pk[i] = f2b(acc[m][n][i] + bn);
                *(u16x4*)&ob[((size_t)(bb * 512 + gn)) * 256 + l] = pk;
            }
        }
    } else {
        float* of = (float*)outp + (size_t)z * oStride;
        const float* rs = resid + (size_t)z * oStride;
#pragma unroll
        for (int m = 0; m < 4; ++m) {
            int gm = m0 + wr * 64 + m * 16 + g * 4;
#pragma unroll
            for (int i = 0; i < 4; ++i) {
                float bm = bias[gm + i];
#pragma unroll
                for (int n = 0; n < 4; ++n) {
                    int gn = n0 + wc * 64 + n * 16 + r;
                    size_t idx = (size_t)(gm + i) * ldo + gn;
                    of[idx] = acc[m][n][i] + bm + rs[idx];
                }
            }
        }
    }
}

// ---------------------------------------------------------------- attention
// Swapped-QK^T structure: lane holds P[s = m*16 + lane&15][l in regs].
// grid: (S/128, B*NH). block 256 (4 waves, 32 s-rows each). LDS 64KB (K + V).
__global__ __launch_bounds__(256, 2) void attn_kernel(
    const u16* __restrict__ q, const u16* __restrict__ kk,
    const u16* __restrict__ vv, u16* __restrict__ ao)
{
    __shared__ __align__(16) u16 sm[32768];
    const int tid = threadIdx.x;
    const int w = tid >> 6, lane = tid & 63;
    const int g = lane >> 4, r = lane & 15;
    const int bh = blockIdx.y, b = bh >> 3, h = bh & 7;
    const int s0 = blockIdx.x * 128;

    {   // stage K (b,l,h*64+e) rows -> sm[l*64 + swz]
        const u16* kbase = kk + ((size_t)b * L_) * C_ + h * 64;
#pragma unroll
        for (int j = 0; j < 8; ++j) {
            int idx = j * 256 + tid;
            int l = idx >> 3, ch = idx & 7;
            u16x8 val = *(const u16x8*)(kbase + (size_t)l * C_ + ch * 8);
            *(u16x8*)&sm[l * 64 + ((ch ^ (l & 7)) << 3)] = val;
        }
        // stage V (b,h,e,l) rows -> sm[16384 + e*256 + swz]
        const u16* vbase = vv + ((size_t)bh * 64) * 256;
#pragma unroll
        for (int j = 0; j < 8; ++j) {
            int idx = j * 256 + tid;
            int e = idx >> 5, ch = idx & 31;
            u16x8 val = *(const u16x8*)(vbase + (size_t)e * 256 + ch * 8);
            *(u16x8*)&sm[16384 + e * 256 + ((ch ^ (e & 7)) << 3)] = val;
        }
    }

    // Q fragments straight from global (read-once)
    const int sw = s0 + w * 32;
    bf16x8 qf[2][2];
#pragma unroll
    for (int m = 0; m < 2; ++m)
#pragma unroll
        for (int kt = 0; kt < 2; ++kt)
            qf[m][kt] = *(const bf16x8*)(q + ((size_t)(b * S_ + sw + m * 16 + r)) * C_
                                         + h * 64 + kt * 32 + g * 8);
    __syncthreads();

    // QK^T swapped: accs[m][n][i] = P-score[s = m*16 + r][l = n*16 + g*4 + i]
    f32x4 accs[2][16];
#pragma unroll
    for (int m = 0; m < 2; ++m)
#pragma unroll
        for (int n = 0; n < 16; ++n) accs[m][n] = f32x4{0.f, 0.f, 0.f, 0.f};
    __builtin_amdgcn_s_setprio(1);
#pragma unroll
    for (int n = 0; n < 16; ++n) {
#pragma unroll
        for (int kt = 0; kt < 2; ++kt) {
            int c = kt * 4 + g;  // e-chunk index
            bf16x8 kf = *(const bf16x8*)&sm[(n * 16 + r) * 64 + ((c ^ (r & 7)) << 3)];
#pragma unroll
            for (int m = 0; m < 2; ++m) accs[m][n] = mfma16(kf, qf[m][kt], accs[m][n]);
        }
    }
    __builtin_amdgcn_s_setprio(0);

    // softmax: in-lane over 64 values, cross-lane over the 4 lanes sharing r
    float inv[2];
#pragma unroll
    for (int m = 0; m < 2; ++m) {
        float mx = accs[m][0][0];
#pragma unroll
        for (int n = 0; n < 16; ++n)
#pragma unroll
            for (int i = 0; i < 4; ++i) mx = fmaxf(mx, accs[m][n][i]);
        mx = fmaxf(mx, __shfl_xor(mx, 16));
        mx = fmaxf(mx, __shfl_xor(mx, 32));
        float sum = 0.f;
#pragma unroll
        for (int n = 0; n < 16; ++n)
#pragma unroll
            for (int i = 0; i < 4; ++i) {
                float e = __expf(accs[m][n][i] - mx);
                accs[m][n][i] = e; sum += e;
            }
        sum += __shfl_xor(sum, 16);
        sum += __shfl_xor(sum, 32);
        inv[m] = 1.0f / sum;
    }

    // PV: per l-chunk c, repack P in-register into A-fragments, then MFMA
    f32x4 acco[2][4];
#pragma unroll
    for (int m = 0; m < 2; ++m)
#pragma unroll
        for (int n = 0; n < 4; ++n) acco[m][n] = f32x4{0.f, 0.f, 0.f, 0.f};

#pragma unroll
    for (int c = 0; c < 8; ++c) {
        bf16x8 pa[2];
#pragma unroll
        for (int m = 0; m < 2; ++m) {
            // x*: n=2c (l = 32c + 4g + i), y*: n=2c+1 (l = 32c + 16 + 4g + i)
            u32 x0 = cvtpk(accs[m][2 * c][0] * inv[m], accs[m][2 * c][1] * inv[m]);
            u32 x1 = cvtpk(accs[m][2 * c][2] * inv[m], accs[m][2 * c][3] * inv[m]);
            u32 y0 = cvtpk(accs[m][2 * c + 1][0] * inv[m], accs[m][2 * c + 1][1] * inv[m]);
            u32 y1 = cvtpk(accs[m][2 * c + 1][2] * inv[m], accs[m][2 * c + 1][3] * inv[m]);
            pl32(x0, y0);   // x0=[x0lo|y0lo]=srcb5:0-data, y0=[x0hi|y0hi]=srcb5:1-data
            pl32(x1, y1);
            pl16(x0, y0);   // -> x0 = w00, y0 = w10
            pl16(x1, y1);   // -> x1 = w01, y1 = w11
            u32x4 pw; pw[0] = x0; pw[1] = x1; pw[2] = y0; pw[3] = y1;
            pa[m] = *(bf16x8*)&pw;
        }
        bf16x8 vf[4];
#pragma unroll
        for (int n = 0; n < 4; ++n) {
            int e = n * 16 + r;
            vf[n] = *(const bf16x8*)&sm[16384 + e * 256 + (((c * 4 + g) ^ (r & 7)) << 3)];
        }
        __builtin_amdgcn_s_setprio(1);
#pragma unroll
        for (int m = 0; m < 2; ++m)
#pragma unroll
            for (int n = 0; n < 4; ++n)
                acco[m][n] = mfma16(pa[m], vf[n], acco[m][n]);
        __builtin_amdgcn_s_setprio(0);
    }

    // write attention output as (b, s, c=h*64+e) bf16
#pragma unroll
    for (int m = 0; m < 2; ++m)
#pragma unroll
        for (int n = 0; n < 4; ++n)
#pragma unroll
            for (int i = 0; i < 4; ++i) {
                int s = sw + m * 16 + g * 4 + i;
                int e = n * 16 + r;
                ao[((size_t)(b * S_ + s)) * C_ + h * 64 + e] = f2b(acco[m][n][i]);
            }
}

// ---------------------------------------------------------------- launch
extern "C" void kernel_launch(void* const* d_in, const int* in_sizes, int n_in,
                              void* d_out, int out_size, void* d_ws, size_t ws_size,
                              hipStream_t stream)
{
    (void)in_sizes; (void)n_in; (void)out_size; (void)ws_size;
    const float* x    = (const float*)d_in[0];
    const float* ctx  = (const float*)d_in[1];
    const float* gn_w = (const float*)d_in[2];
    const float* gn_b = (const float*)d_in[3];
    const float* ln_w = (const float*)d_in[4];
    const float* ln_b = (const float*)d_in[5];
    const float* q_w  = (const float*)d_in[6];
    const float* q_b  = (const float*)d_in[7];
    const float* k_w  = (const float*)d_in[8];
    const float* k_b  = (const float*)d_in[9];
    const float* v_w  = (const float*)d_in[10];
    const float* v_b  = (const float*)d_in[11];
    const float* p_w  = (const float*)d_in[12];
    const float* p_b  = (const float*)d_in[13];
    float* out = (float*)d_out;

    char* ws = (char*)d_ws;
    constexpr size_t WS_WQ   = 0;
    constexpr size_t WS_WK   = WS_WQ + (size_t)512 * 512 * 2;
    constexpr size_t WS_WV   = WS_WK + (size_t)512 * 768 * 2;
    constexpr size_t WS_WP   = WS_WV + (size_t)512 * 768 * 2;
    constexpr size_t WS_PART = WS_WP + (size_t)512 * 512 * 2;
    constexpr size_t WS_STAT = WS_PART + (size_t)16 * 64 * 2 * 4;
    constexpr size_t WS_CTXN = WS_STAT + 256;
    constexpr size_t WS_K    = WS_CTXN + (size_t)512 * 768 * 2;
    constexpr size_t WS_V    = WS_K + (size_t)2 * 8 * 256 * 64 * 2;
    constexpr size_t WS_Q    = WS_V + (size_t)2 * 8 * 256 * 64 * 2;
    constexpr size_t WS_H    = WS_Q + (size_t)2 * 32768 * 512 * 2;

    u16* wq = (u16*)(ws + WS_WQ);
    u16* wk = (u16*)(ws + WS_WK);
    u16* wv = (u16*)(ws + WS_WV);
    u16* wp = (u16*)(ws + WS_WP);
    float* part  = (float*)(ws + WS_PART);
    float* stats = (float*)(ws + WS_STAT);
    u16* ctxn = (u16*)(ws + WS_CTXN);
    u16* kt   = (u16*)(ws + WS_K);
    u16* vt   = (u16*)(ws + WS_V);
    u16* qt   = (u16*)(ws + WS_Q);
    u16* ht   = (u16*)(ws + WS_H);
    u16* ao   = ht;  // h dead after Q-GEMM; reuse for attention output

    const size_t bsc = (size_t)S_ * C_;  // per-batch (s,c)/(c,s) stride

    cvt_w<<<dim3(384, 4), 256, 0, stream>>>(q_w, k_w, v_w, p_w, wq, wk, wv, wp);
    gn_partial<<<dim3(64, 16), 256, 0, stream>>>(x, part);
    gn_final<<<16, 64, 0, stream>>>(part, stats);
    gn_apply<<<dim3(512, 8, 2), 256, 0, stream>>>(x, stats, gn_w, gn_b, ht);
    ln_ctx<<<512, 256, 0, stream>>>(ctx, ln_w, ln_b, ctxn);
    // Q = h . Wq^T  (scale folded), out (b,s,o) bf16
    gemm_nt<0><<<dim3(256, 4, 2), 256, 0, stream>>>(ht, wq, q_b, qt, nullptr,
                                                    512, 512, bsc, 0, bsc, 0.125f);
    // K = ctxn . Wk^T, out (b*l, o) bf16
    gemm_nt<0><<<dim3(4, 4, 1), 256, 0, stream>>>(ctxn, wk, k_b, kt, nullptr,
                                                  768, 512, 0, 0, 0, 1.0f);
    // V = ctxn . Wv^T, scattered to (b,h,e,l) bf16
    gemm_nt<1><<<dim3(4, 4, 1), 256, 0, stream>>>(ctxn, wv, v_b, vt, nullptr,
                                                  768, 0, 0, 0, 0, 1.0f);
    attn_kernel<<<dim3(256, 16), 256, 0, stream>>>(qt, kt, vt, ao);
    // out = Wp . ao^T + bias + x  (fp32, (b,c,s))
    gemm_nt<2><<<dim3(4, 256, 2), 256, 0, stream>>>(wp, ao, p_b, out, x,
                                                    512, S_, 0, bsc, bsc, 1.0f);
}

// Round 3
// 285.807 us; speedup vs baseline: 1.1563x; 1.0770x over previous
//
#include <hip/hip_runtime.h>

typedef unsigned short u16;
typedef unsigned int u32;
typedef __attribute__((ext_vector_type(4))) float f32x4;
typedef __attribute__((ext_vector_type(8))) short bf16x8;
typedef __attribute__((ext_vector_type(8))) u16 u16x8;
typedef __attribute__((ext_vector_type(4))) u16 u16x4;
typedef __attribute__((ext_vector_type(4))) u32 u32x4;

#define DEVI __device__ __forceinline__

constexpr int C_ = 512, S_ = 32768, L_ = 256, CTX_ = 768;

DEVI u16 f2b(float f) {  // fp32 -> bf16 RNE
    union { float f; unsigned u; } x; x.f = f;
    unsigned r = x.u + 0x7fffu + ((x.u >> 16) & 1u);
    return (u16)(r >> 16);
}

DEVI f32x4 mfma16(bf16x8 a, bf16x8 b, f32x4 c) {
    return __builtin_amdgcn_mfma_f32_16x16x32_bf16(a, b, c, 0, 0, 0);
}

DEVI void gload16(const void* g, void* l) {
    __builtin_amdgcn_global_load_lds(
        (const __attribute__((address_space(1))) void*)g,
        (__attribute__((address_space(3))) void*)l, 16, 0, 0);
}

DEVI u32 cvtpk(float lo, float hi) {  // {hi_bf16, lo_bf16}
    u32 d;
    asm("v_cvt_pk_bf16_f32 %0, %1, %2" : "=v"(d) : "v"(lo), "v"(hi));
    return d;
}
DEVI void pl32(u32& a, u32& b) {
    asm volatile("v_permlane32_swap_b32 %0, %1" : "+v"(a), "+v"(b));
}
DEVI void pl16(u32& a, u32& b) {
    asm volatile("v_permlane16_swap_b32 %0, %1" : "+v"(a), "+v"(b));
}

// ---------------------------------------------------------------- weights cvt
__global__ __launch_bounds__(256) void cvt_w(
    const float* __restrict__ a0, const float* __restrict__ a1,
    const float* __restrict__ a2, const float* __restrict__ a3,
    u16* __restrict__ o0, u16* __restrict__ o1,
    u16* __restrict__ o2, u16* __restrict__ o3)
{
    int which = blockIdx.y;
    const float* src = which == 0 ? a0 : which == 1 ? a1 : which == 2 ? a2 : a3;
    u16* dst = which == 0 ? o0 : which == 1 ? o1 : which == 2 ? o2 : o3;
    int n4 = (which == 1 || which == 2) ? (512 * 768 / 4) : (512 * 512 / 4);
    int i = blockIdx.x * 256 + threadIdx.x;
    if (i < n4) {
        float4 v = ((const float4*)src)[i];
        u16x4 o; o[0] = f2b(v.x); o[1] = f2b(v.y); o[2] = f2b(v.z); o[3] = f2b(v.w);
        ((u16x4*)dst)[i] = o;
    }
}

// ---------------------------------------------------------------- GN stats
__global__ __launch_bounds__(256) void gn_partial(const float* __restrict__ x,
                                                  float* __restrict__ part)
{
    const int bg = blockIdx.y, blk = blockIdx.x, tid = threadIdx.x;
    const float* base = x + (size_t)bg * 64 * S_ + (size_t)blk * 512;
    float s1 = 0.f, s2 = 0.f;
    for (int c = 0; c < 64; ++c) {
        const float* row = base + (size_t)c * S_;
        float v0 = row[tid], v1 = row[tid + 256];
        s1 += v0 + v1; s2 += v0 * v0 + v1 * v1;
    }
    for (int m = 1; m < 64; m <<= 1) { s1 += __shfl_xor(s1, m); s2 += __shfl_xor(s2, m); }
    __shared__ float a1[4], a2[4];
    int w = tid >> 6, lane = tid & 63;
    if (lane == 0) { a1[w] = s1; a2[w] = s2; }
    __syncthreads();
    if (tid == 0) {
        part[(bg * 64 + blk) * 2 + 0] = a1[0] + a1[1] + a1[2] + a1[3];
        part[(bg * 64 + blk) * 2 + 1] = a2[0] + a2[1] + a2[2] + a2[3];
    }
}

__global__ __launch_bounds__(64) void gn_final(const float* __restrict__ part,
                                               float* __restrict__ stats)
{
    int bg = blockIdx.x, tid = threadIdx.x;
    float s1 = part[(bg * 64 + tid) * 2], s2 = part[(bg * 64 + tid) * 2 + 1];
    for (int m = 1; m < 64; m <<= 1) { s1 += __shfl_xor(s1, m); s2 += __shfl_xor(s2, m); }
    if (tid == 0) {
        const float invN = 1.0f / (64.0f * (float)S_);
        float mu = s1 * invN, var = s2 * invN - mu * mu;
        stats[bg * 2] = mu;
        stats[bg * 2 + 1] = rsqrtf(var + 1e-5f);
    }
}

// ------------------------------------------- GN apply + transpose to (b,s,c) bf16
__global__ __launch_bounds__(256) void gn_apply(
    const float* __restrict__ x, const float* __restrict__ stats,
    const float* __restrict__ gw, const float* __restrict__ gb,
    u16* __restrict__ ht)
{
    __shared__ float tile[64][65];
    const int tid = threadIdx.x, sl = tid & 63, c4 = tid >> 6;
    const int s0 = blockIdx.x * 64, c0 = blockIdx.y * 64, b = blockIdx.z;
    const int bg = b * 8 + (c0 >> 6);
    const float mu = stats[bg * 2], rstd = stats[bg * 2 + 1];
#pragma unroll
    for (int i = 0; i < 16; ++i) {
        int cl = c4 * 16 + i;
        float wv = gw[c0 + cl], bv = gb[c0 + cl];
        float v = x[((size_t)(b * C_ + c0 + cl)) * S_ + s0 + sl];
        tile[sl][cl] = (v - mu) * rstd * wv + bv;
    }
    __syncthreads();
#pragma unroll
    for (int i = 0; i < 16; ++i) {
        int so = c4 * 16 + i;
        ht[((size_t)(b * S_ + s0 + so)) * C_ + c0 + sl] = f2b(tile[so][sl]);
    }
}

// ---------------------------------------------------------------- LayerNorm(ctx)
__global__ __launch_bounds__(256) void ln_ctx(
    const float* __restrict__ ctx, const float* __restrict__ lw,
    const float* __restrict__ lb, u16* __restrict__ cn)
{
    const int row = blockIdx.x, tid = threadIdx.x;
    const float* p = ctx + (size_t)row * CTX_;
    float v0 = p[tid], v1 = p[tid + 256], v2 = p[tid + 512];
    float s1 = v0 + v1 + v2, s2 = v0 * v0 + v1 * v1 + v2 * v2;
    for (int m = 1; m < 64; m <<= 1) { s1 += __shfl_xor(s1, m); s2 += __shfl_xor(s2, m); }
    __shared__ float a1[4], a2[4];
    int w = tid >> 6, lane = tid & 63;
    if (lane == 0) { a1[w] = s1; a2[w] = s2; }
    __syncthreads();
    s1 = a1[0] + a1[1] + a1[2] + a1[3];
    s2 = a2[0] + a2[1] + a2[2] + a2[3];
    const float invN = 1.0f / 768.0f;
    float mu = s1 * invN, rstd = rsqrtf(s2 * invN - mu * mu + 1e-5f);
    u16* o = cn + (size_t)row * CTX_;
    o[tid]       = f2b((v0 - mu) * rstd * lw[tid]       + lb[tid]);
    o[tid + 256] = f2b((v1 - mu) * rstd * lw[tid + 256] + lb[tid + 256]);
    o[tid + 512] = f2b((v2 - mu) * rstd * lw[tid + 512] + lb[tid + 512]);
}

// ---------------------------------------------------------------- NT-GEMM
// C[m][n] = sum_k A[m*K+k] * B[n*K+k]  (both K-contiguous bf16)
// Pipelined: 4 LDS buffers, 3-deep prefetch, counted vmcnt, raw s_barrier.
// LDS layout per buffer: 64 rows x 128B; logical (mrow,g-chunk[16B]) stored at
// row = mrow>>1, slot = ((mrow&1)*4+g) ^ ((mrow>>1)&7)  (conflict-free reads).
// MODE 0: bf16 out[m*ldo+n] = (acc + bias[n]) * scale
// MODE 2: f32  out[m*ldo+n] = acc + bias[m] + resid[m*ldo+n]
// MODE 3: z==0 -> MODE0-style to outp (K proj); z==1 -> V-scatter to outp2
template <int MODE>
__global__ __launch_bounds__(256, 2) void gemm_nt(
    const u16* __restrict__ A, const u16* __restrict__ Bp,
    const float* __restrict__ bias, void* __restrict__ outp,
    const float* __restrict__ resid, int K, int ldo,
    size_t aStride, size_t bStride, size_t oStride, float scale,
    const u16* __restrict__ Bp2, const float* __restrict__ bias2,
    void* __restrict__ outp2)
{
    __shared__ __align__(16) u16 lA[4][4096];
    __shared__ __align__(16) u16 lB[4][4096];
    const int tid = threadIdx.x;
    const int w = tid >> 6, lane = tid & 63;
    const int g = lane >> 4, r = lane & 15;
    const int m0 = blockIdx.x * 128, n0 = blockIdx.y * 128;
    const int z = blockIdx.z;
    A += (size_t)z * aStride;
    const u16* Bsel = Bp;
    if constexpr (MODE == 3) { if (z) Bsel = Bp2; }
    Bsel += (size_t)z * bStride;

    // staging source pre-swizzle (rule #21: linear LDS dest, permuted source)
    const int l8 = lane & 7, lh = lane >> 3;
    const int u_ = l8 ^ lh;                 // slot-at-dest ^ row&7
    const int mro = (lh << 1) + (u_ >> 2);  // row offset within 16-row chunk
    const int kco = (u_ & 3) * 8;           // k offset (elements) within 32
    const int wr = w >> 1, wc = w & 1;
    const int nt = K >> 5;

    f32x4 acc[4][4];
#pragma unroll
    for (int m = 0; m < 4; ++m)
#pragma unroll
        for (int n = 0; n < 4; ++n) acc[m][n] = f32x4{0.f, 0.f, 0.f, 0.f};

#define STAGE_T(t) {                                                           \
    int bi_ = (t) & 3;                                                         \
    size_t ko_ = (size_t)((t) * 32 + kco);                                     \
    _Pragma("unroll")                                                          \
    for (int j = 0; j < 2; ++j) {                                              \
        int grow_ = w * 32 + j * 16 + mro;                                     \
        gload16(A + (size_t)(m0 + grow_) * K + ko_,                            \
                &lA[bi_][(w * 16 + j * 8) << 6]);                              \
        gload16(Bsel + (size_t)(n0 + grow_) * K + ko_,                         \
                &lB[bi_][(w * 16 + j * 8) << 6]);                              \
    } }

    STAGE_T(0); STAGE_T(1); STAGE_T(2);

    for (int t = 0; t < nt; ++t) {
        asm volatile("s_waitcnt lgkmcnt(0)" ::: "memory");
        if (t < nt - 2)      asm volatile("s_waitcnt vmcnt(8)" ::: "memory");
        else if (t == nt - 2) asm volatile("s_waitcnt vmcnt(4)" ::: "memory");
        else                  asm volatile("s_waitcnt vmcnt(0)" ::: "memory");
        __builtin_amdgcn_s_barrier();
        asm volatile("" ::: "memory");
        const int bi = t & 3;
        bf16x8 af[4], bf_[4];
#pragma unroll
        for (int m = 0; m < 4; ++m) {
            int row = wr * 32 + m * 8 + (r >> 1);
            int slot = (((r & 1) << 2) + g) ^ ((r >> 1) & 7);
            af[m] = *(const bf16x8*)&lA[bi][(row << 6) + (slot << 3)];
        }
#pragma unroll
        for (int n = 0; n < 4; ++n) {
            int row = wc * 32 + n * 8 + (r >> 1);
            int slot = (((r & 1) << 2) + g) ^ ((r >> 1) & 7);
            bf_[n] = *(const bf16x8*)&lB[bi][(row << 6) + (slot << 3)];
        }
        if (t + 3 < nt) STAGE_T(t + 3);
#pragma unroll
        for (int m = 0; m < 4; ++m)
#pragma unroll
            for (int n = 0; n < 4; ++n)
                acc[m][n] = mfma16(af[m], bf_[n], acc[m][n]);
    }
#undef STAGE_T

    if constexpr (MODE == 0) {
        u16* ob = (u16*)outp + (size_t)z * oStride;
#pragma unroll
        for (int n = 0; n < 4; ++n) {
            int gn = n0 + wc * 64 + n * 16 + r;
            float bn = bias[gn] * scale;
#pragma unroll
            for (int m = 0; m < 4; ++m) {
                int gm = m0 + wr * 64 + m * 16 + g * 4;
#pragma unroll
                for (int i = 0; i < 4; ++i)
                    ob[(size_t)(gm + i) * ldo + gn] = f2b(acc[m][n][i] * scale + bn);
            }
        }
    } else if constexpr (MODE == 2) {
        float* of = (float*)outp + (size_t)z * oStride;
        const float* rs = resid + (size_t)z * oStride;
#pragma unroll
        for (int m = 0; m < 4; ++m) {
            int gm = m0 + wr * 64 + m * 16 + g * 4;
#pragma unroll
            for (int i = 0; i < 4; ++i) {
                float bm = bias[gm + i];
#pragma unroll
                for (int n = 0; n < 4; ++n) {
                    int gn = n0 + wc * 64 + n * 16 + r;
                    size_t idx = (size_t)(gm + i) * ldo + gn;
                    of[idx] = acc[m][n][i] + bm + rs[idx];
                }
            }
        }
    } else if constexpr (MODE == 3) {
        if (z == 0) {  // K projection: (b*l, o) bf16
            u16* ob = (u16*)outp;
#pragma unroll
            for (int n = 0; n < 4; ++n) {
                int gn = n0 + wc * 64 + n * 16 + r;
                float bn = bias[gn];
#pragma unroll
                for (int m = 0; m < 4; ++m) {
                    int gm = m0 + wr * 64 + m * 16 + g * 4;
#pragma unroll
                    for (int i = 0; i < 4; ++i)
                        ob[(size_t)(gm + i) * ldo + gn] = f2b(acc[m][n][i] + bn);
                }
            }
        } else {       // V projection scattered to (b,h,e,l) bf16
            u16* ob = (u16*)outp2;
#pragma unroll
            for (int n = 0; n < 4; ++n) {
                int gn = n0 + wc * 64 + n * 16 + r;
                float bn = bias2[gn];
#pragma unroll
                for (int m = 0; m < 4; ++m) {
                    int gm = m0 + wr * 64 + m * 16 + g * 4;
                    int bb = gm >> 8, l = gm & 255;
                    u16x4 pk;
#pragma unroll
                    for (int i = 0; i < 4; ++i) pk[i] = f2b(acc[m][n][i] + bn);
                    *(u16x4*)&ob[((size_t)(bb * 512 + gn)) * 256 + l] = pk;
                }
            }
        }
    }
}

// ---------------------------------------------------------------- attention
// Swapped-QK^T structure: lane holds P[s = m*16 + lane&15][l in regs].
// grid: (S/128, B*NH). block 256 (4 waves, 32 s-rows each). LDS 64KB (K + V).
__global__ __launch_bounds__(256, 2) void attn_kernel(
    const u16* __restrict__ q, const u16* __restrict__ kk,
    const u16* __restrict__ vv, u16* __restrict__ ao)
{
    __shared__ __align__(16) u16 sm[32768];
    const int tid = threadIdx.x;
    const int w = tid >> 6, lane = tid & 63;
    const int g = lane >> 4, r = lane & 15;
    const int bh = blockIdx.y, b = bh >> 3, h = bh & 7;
    const int s0 = blockIdx.x * 128;

    {   // stage K (b,l,h*64+e) rows -> sm[l*64 + swz]
        const u16* kbase = kk + ((size_t)b * L_) * C_ + h * 64;
#pragma unroll
        for (int j = 0; j < 8; ++j) {
            int idx = j * 256 + tid;
            int l = idx >> 3, ch = idx & 7;
            u16x8 val = *(const u16x8*)(kbase + (size_t)l * C_ + ch * 8);
            *(u16x8*)&sm[l * 64 + ((ch ^ (l & 7)) << 3)] = val;
        }
        // stage V (b,h,e,l) rows -> sm[16384 + e*256 + swz]
        const u16* vbase = vv + ((size_t)bh * 64) * 256;
#pragma unroll
        for (int j = 0; j < 8; ++j) {
            int idx = j * 256 + tid;
            int e = idx >> 5, ch = idx & 31;
            u16x8 val = *(const u16x8*)(vbase + (size_t)e * 256 + ch * 8);
            *(u16x8*)&sm[16384 + e * 256 + ((ch ^ (e & 7)) << 3)] = val;
        }
    }

    // Q fragments straight from global (read-once)
    const int sw = s0 + w * 32;
    bf16x8 qf[2][2];
#pragma unroll
    for (int m = 0; m < 2; ++m)
#pragma unroll
        for (int kt = 0; kt < 2; ++kt)
            qf[m][kt] = *(const bf16x8*)(q + ((size_t)(b * S_ + sw + m * 16 + r)) * C_
                                         + h * 64 + kt * 32 + g * 8);
    __syncthreads();

    // QK^T swapped: accs[m][n][i] = P-score[s = m*16 + r][l = n*16 + g*4 + i]
    f32x4 accs[2][16];
#pragma unroll
    for (int m = 0; m < 2; ++m)
#pragma unroll
        for (int n = 0; n < 16; ++n) accs[m][n] = f32x4{0.f, 0.f, 0.f, 0.f};
    __builtin_amdgcn_s_setprio(1);
#pragma unroll
    for (int n = 0; n < 16; ++n) {
#pragma unroll
        for (int kt = 0; kt < 2; ++kt) {
            int c = kt * 4 + g;  // e-chunk index
            bf16x8 kf = *(const bf16x8*)&sm[(n * 16 + r) * 64 + ((c ^ (r & 7)) << 3)];
#pragma unroll
            for (int m = 0; m < 2; ++m) accs[m][n] = mfma16(kf, qf[m][kt], accs[m][n]);
        }
    }
    __builtin_amdgcn_s_setprio(0);

    // softmax: in-lane over 64 values, cross-lane over the 4 lanes sharing r
    float inv[2];
#pragma unroll
    for (int m = 0; m < 2; ++m) {
        float mx = accs[m][0][0];
#pragma unroll
        for (int n = 0; n < 16; ++n)
#pragma unroll
            for (int i = 0; i < 4; ++i) mx = fmaxf(mx, accs[m][n][i]);
        mx = fmaxf(mx, __shfl_xor(mx, 16));
        mx = fmaxf(mx, __shfl_xor(mx, 32));
        float sum = 0.f;
#pragma unroll
        for (int n = 0; n < 16; ++n)
#pragma unroll
            for (int i = 0; i < 4; ++i) {
                float e = __expf(accs[m][n][i] - mx);
                accs[m][n][i] = e; sum += e;
            }
        sum += __shfl_xor(sum, 16);
        sum += __shfl_xor(sum, 32);
        inv[m] = 1.0f / sum;
    }

    // PV: per l-chunk c, repack P in-register into A-fragments, then MFMA
    f32x4 acco[2][4];
#pragma unroll
    for (int m = 0; m < 2; ++m)
#pragma unroll
        for (int n = 0; n < 4; ++n) acco[m][n] = f32x4{0.f, 0.f, 0.f, 0.f};

#pragma unroll
    for (int c = 0; c < 8; ++c) {
        bf16x8 pa[2];
#pragma unroll
        for (int m = 0; m < 2; ++m) {
            u32 x0 = cvtpk(accs[m][2 * c][0] * inv[m], accs[m][2 * c][1] * inv[m]);
            u32 x1 = cvtpk(accs[m][2 * c][2] * inv[m], accs[m][2 * c][3] * inv[m]);
            u32 y0 = cvtpk(accs[m][2 * c + 1][0] * inv[m], accs[m][2 * c + 1][1] * inv[m]);
            u32 y1 = cvtpk(accs[m][2 * c + 1][2] * inv[m], accs[m][2 * c + 1][3] * inv[m]);
            pl32(x0, y0);
            pl32(x1, y1);
            pl16(x0, y0);
            pl16(x1, y1);
            u32x4 pw; pw[0] = x0; pw[1] = x1; pw[2] = y0; pw[3] = y1;
            pa[m] = *(bf16x8*)&pw;
        }
        bf16x8 vf[4];
#pragma unroll
        for (int n = 0; n < 4; ++n) {
            int e = n * 16 + r;
            vf[n] = *(const bf16x8*)&sm[16384 + e * 256 + (((c * 4 + g) ^ (r & 7)) << 3)];
        }
        __builtin_amdgcn_s_setprio(1);
#pragma unroll
        for (int m = 0; m < 2; ++m)
#pragma unroll
            for (int n = 0; n < 4; ++n)
                acco[m][n] = mfma16(pa[m], vf[n], acco[m][n]);
        __builtin_amdgcn_s_setprio(0);
    }

    // write attention output as (b, s, c=h*64+e) bf16
#pragma unroll
    for (int m = 0; m < 2; ++m)
#pragma unroll
        for (int n = 0; n < 4; ++n)
#pragma unroll
            for (int i = 0; i < 4; ++i) {
                int s = sw + m * 16 + g * 4 + i;
                int e = n * 16 + r;
                ao[((size_t)(b * S_ + s)) * C_ + h * 64 + e] = f2b(acco[m][n][i]);
            }
}

// ---------------------------------------------------------------- launch
extern "C" void kernel_launch(void* const* d_in, const int* in_sizes, int n_in,
                              void* d_out, int out_size, void* d_ws, size_t ws_size,
                              hipStream_t stream)
{
    (void)in_sizes; (void)n_in; (void)out_size; (void)ws_size;
    const float* x    = (const float*)d_in[0];
    const float* ctx  = (const float*)d_in[1];
    const float* gn_w = (const float*)d_in[2];
    const float* gn_b = (const float*)d_in[3];
    const float* ln_w = (const float*)d_in[4];
    const float* ln_b = (const float*)d_in[5];
    const float* q_w  = (const float*)d_in[6];
    const float* q_b  = (const float*)d_in[7];
    const float* k_w  = (const float*)d_in[8];
    const float* k_b  = (const float*)d_in[9];
    const float* v_w  = (const float*)d_in[10];
    const float* v_b  = (const float*)d_in[11];
    const float* p_w  = (const float*)d_in[12];
    const float* p_b  = (const float*)d_in[13];
    float* out = (float*)d_out;

    char* ws = (char*)d_ws;
    constexpr size_t WS_WQ   = 0;
    constexpr size_t WS_WK   = WS_WQ + (size_t)512 * 512 * 2;
    constexpr size_t WS_WV   = WS_WK + (size_t)512 * 768 * 2;
    constexpr size_t WS_WP   = WS_WV + (size_t)512 * 768 * 2;
    constexpr size_t WS_PART = WS_WP + (size_t)512 * 512 * 2;
    constexpr size_t WS_STAT = WS_PART + (size_t)16 * 64 * 2 * 4;
    constexpr size_t WS_CTXN = WS_STAT + 256;
    constexpr size_t WS_K    = WS_CTXN + (size_t)512 * 768 * 2;
    constexpr size_t WS_V    = WS_K + (size_t)2 * 8 * 256 * 64 * 2;
    constexpr size_t WS_Q    = WS_V + (size_t)2 * 8 * 256 * 64 * 2;
    constexpr size_t WS_H    = WS_Q + (size_t)2 * 32768 * 512 * 2;

    u16* wq = (u16*)(ws + WS_WQ);
    u16* wk = (u16*)(ws + WS_WK);
    u16* wv = (u16*)(ws + WS_WV);
    u16* wp = (u16*)(ws + WS_WP);
    float* part  = (float*)(ws + WS_PART);
    float* stats = (float*)(ws + WS_STAT);
    u16* ctxn = (u16*)(ws + WS_CTXN);
    u16* kt   = (u16*)(ws + WS_K);
    u16* vt   = (u16*)(ws + WS_V);
    u16* qt   = (u16*)(ws + WS_Q);
    u16* ht   = (u16*)(ws + WS_H);
    u16* ao   = ht;  // h dead after Q-GEMM; reuse for attention output

    const size_t bsc = (size_t)S_ * C_;  // per-batch (s,c)/(c,s) stride

    cvt_w<<<dim3(384, 4), 256, 0, stream>>>(q_w, k_w, v_w, p_w, wq, wk, wv, wp);
    gn_partial<<<dim3(64, 16), 256, 0, stream>>>(x, part);
    gn_final<<<16, 64, 0, stream>>>(part, stats);
    gn_apply<<<dim3(512, 8, 2), 256, 0, stream>>>(x, stats, gn_w, gn_b, ht);
    ln_ctx<<<512, 256, 0, stream>>>(ctx, ln_w, ln_b, ctxn);
    // Q = h . Wq^T  (scale folded), out (b,s,o) bf16
    gemm_nt<0><<<dim3(256, 4, 2), 256, 0, stream>>>(ht, wq, q_b, qt, nullptr,
                                                    512, 512, bsc, 0, bsc, 0.125f,
                                                    nullptr, nullptr, nullptr);
    // K,V = ctxn . W^T in one launch (z selects)
    gemm_nt<3><<<dim3(4, 4, 2), 256, 0, stream>>>(ctxn, wk, k_b, kt, nullptr,
                                                  768, 512, 0, 0, 0, 1.0f,
                                                  wv, v_b, vt);
    attn_kernel<<<dim3(256, 16), 256, 0, stream>>>(qt, kt, vt, ao);
    // out = Wp . ao^T + bias + x  (fp32, (b,c,s))
    gemm_nt<2><<<dim3(4, 256, 2), 256, 0, stream>>>(wp, ao, p_b, out, x,
                                                    512, S_, 0, bsc, bsc, 1.0f,
                                                    nullptr, nullptr, nullptr);
}

// Round 4
// 279.519 us; speedup vs baseline: 1.1823x; 1.0225x over previous
//
#include <hip/hip_runtime.h>

typedef unsigned short u16;
typedef unsigned int u32;
typedef __attribute__((ext_vector_type(4))) float f32x4;
typedef __attribute__((ext_vector_type(8))) short bf16x8;
typedef __attribute__((ext_vector_type(8))) u16 u16x8;
typedef __attribute__((ext_vector_type(4))) u16 u16x4;
typedef __attribute__((ext_vector_type(4))) u32 u32x4;

#define DEVI __device__ __forceinline__

constexpr int C_ = 512, S_ = 32768, L_ = 256, CTX_ = 768;

DEVI u16 f2b(float f) {  // fp32 -> bf16 RNE
    union { float f; unsigned u; } x; x.f = f;
    unsigned r = x.u + 0x7fffu + ((x.u >> 16) & 1u);
    return (u16)(r >> 16);
}

DEVI f32x4 mfma16(bf16x8 a, bf16x8 b, f32x4 c) {
    return __builtin_amdgcn_mfma_f32_16x16x32_bf16(a, b, c, 0, 0, 0);
}

DEVI void gload16(const void* g, void* l) {
    __builtin_amdgcn_global_load_lds(
        (const __attribute__((address_space(1))) void*)g,
        (__attribute__((address_space(3))) void*)l, 16, 0, 0);
}

DEVI u32 cvtpk(float lo, float hi) {  // {hi_bf16, lo_bf16}
    u32 d;
    asm("v_cvt_pk_bf16_f32 %0, %1, %2" : "=v"(d) : "v"(lo), "v"(hi));
    return d;
}
DEVI void pl32(u32& a, u32& b) {
    asm volatile("v_permlane32_swap_b32 %0, %1" : "+v"(a), "+v"(b));
}
DEVI void pl16(u32& a, u32& b) {
    asm volatile("v_permlane16_swap_b32 %0, %1" : "+v"(a), "+v"(b));
}

// ---------------------------------------------------------------- weights cvt
__global__ __launch_bounds__(256) void cvt_w(
    const float* __restrict__ a0, const float* __restrict__ a1,
    const float* __restrict__ a2, const float* __restrict__ a3,
    u16* __restrict__ o0, u16* __restrict__ o1,
    u16* __restrict__ o2, u16* __restrict__ o3)
{
    int which = blockIdx.y;
    const float* src = which == 0 ? a0 : which == 1 ? a1 : which == 2 ? a2 : a3;
    u16* dst = which == 0 ? o0 : which == 1 ? o1 : which == 2 ? o2 : o3;
    int n4 = (which == 1 || which == 2) ? (512 * 768 / 4) : (512 * 512 / 4);
    int i = blockIdx.x * 256 + threadIdx.x;
    if (i < n4) {
        float4 v = ((const float4*)src)[i];
        u16x4 o; o[0] = f2b(v.x); o[1] = f2b(v.y); o[2] = f2b(v.z); o[3] = f2b(v.w);
        ((u16x4*)dst)[i] = o;
    }
}

// ---------------------------------------------------------------- GN stats
__global__ __launch_bounds__(256) void gn_partial(const float* __restrict__ x,
                                                  float* __restrict__ part)
{
    const int bg = blockIdx.y, blk = blockIdx.x, tid = threadIdx.x;
    const float* base = x + (size_t)bg * 64 * S_ + (size_t)blk * 1024 + tid * 4;
    float s1 = 0.f, s2 = 0.f;
    for (int c = 0; c < 64; ++c) {
        float4 v = *(const float4*)(base + (size_t)c * S_);
        s1 += v.x + v.y + v.z + v.w;
        s2 += v.x * v.x + v.y * v.y + v.z * v.z + v.w * v.w;
    }
    for (int m = 1; m < 64; m <<= 1) { s1 += __shfl_xor(s1, m); s2 += __shfl_xor(s2, m); }
    __shared__ float a1[4], a2[4];
    int w = tid >> 6, lane = tid & 63;
    if (lane == 0) { a1[w] = s1; a2[w] = s2; }
    __syncthreads();
    if (tid == 0) {
        part[(bg * 32 + blk) * 2 + 0] = a1[0] + a1[1] + a1[2] + a1[3];
        part[(bg * 32 + blk) * 2 + 1] = a2[0] + a2[1] + a2[2] + a2[3];
    }
}

__global__ __launch_bounds__(64) void gn_final(const float* __restrict__ part,
                                               float* __restrict__ stats)
{
    int bg = blockIdx.x, tid = threadIdx.x;
    float s1 = tid < 32 ? part[(bg * 32 + tid) * 2] : 0.f;
    float s2 = tid < 32 ? part[(bg * 32 + tid) * 2 + 1] : 0.f;
    for (int m = 1; m < 32; m <<= 1) { s1 += __shfl_xor(s1, m); s2 += __shfl_xor(s2, m); }
    if (tid == 0) {
        const float invN = 1.0f / (64.0f * (float)S_);
        float mu = s1 * invN, var = s2 * invN - mu * mu;
        stats[bg * 2] = mu;
        stats[bg * 2 + 1] = rsqrtf(var + 1e-5f);
    }
}

// ------------------------------------------- GN apply + transpose to (b,s,c) bf16
__global__ __launch_bounds__(256) void gn_apply(
    const float* __restrict__ x, const float* __restrict__ stats,
    const float* __restrict__ gw, const float* __restrict__ gb,
    u16* __restrict__ ht)
{
    __shared__ float tile[64][65];
    const int tid = threadIdx.x, sl = tid & 63, c4 = tid >> 6;
    const int s0 = blockIdx.x * 64, c0 = blockIdx.y * 64, b = blockIdx.z;
    const int bg = b * 8 + (c0 >> 6);
    const float mu = stats[bg * 2], rstd = stats[bg * 2 + 1];
#pragma unroll
    for (int i = 0; i < 16; ++i) {
        int cl = c4 * 16 + i;
        float wv = gw[c0 + cl], bv = gb[c0 + cl];
        float v = x[((size_t)(b * C_ + c0 + cl)) * S_ + s0 + sl];
        tile[sl][cl] = (v - mu) * rstd * wv + bv;
    }
    __syncthreads();
#pragma unroll
    for (int i = 0; i < 16; ++i) {
        int so = c4 * 16 + i;
        ht[((size_t)(b * S_ + s0 + so)) * C_ + c0 + sl] = f2b(tile[so][sl]);
    }
}

// ---------------------------------------------------------------- LayerNorm(ctx)
__global__ __launch_bounds__(256) void ln_ctx(
    const float* __restrict__ ctx, const float* __restrict__ lw,
    const float* __restrict__ lb, u16* __restrict__ cn)
{
    const int row = blockIdx.x, tid = threadIdx.x;
    const float* p = ctx + (size_t)row * CTX_;
    float v0 = p[tid], v1 = p[tid + 256], v2 = p[tid + 512];
    float s1 = v0 + v1 + v2, s2 = v0 * v0 + v1 * v1 + v2 * v2;
    for (int m = 1; m < 64; m <<= 1) { s1 += __shfl_xor(s1, m); s2 += __shfl_xor(s2, m); }
    __shared__ float a1[4], a2[4];
    int w = tid >> 6, lane = tid & 63;
    if (lane == 0) { a1[w] = s1; a2[w] = s2; }
    __syncthreads();
    s1 = a1[0] + a1[1] + a1[2] + a1[3];
    s2 = a2[0] + a2[1] + a2[2] + a2[3];
    const float invN = 1.0f / 768.0f;
    float mu = s1 * invN, rstd = rsqrtf(s2 * invN - mu * mu + 1e-5f);
    u16* o = cn + (size_t)row * CTX_;
    o[tid]       = f2b((v0 - mu) * rstd * lw[tid]       + lb[tid]);
    o[tid + 256] = f2b((v1 - mu) * rstd * lw[tid + 256] + lb[tid + 256]);
    o[tid + 512] = f2b((v2 - mu) * rstd * lw[tid + 512] + lb[tid + 512]);
}

// ---------------------------------------------------------------- NT-GEMM
// C[m][n] = sum_k A[m*K+k] * B[n*K+k]  (both K-contiguous bf16)
// Double-buffered (32KB LDS), 1 barrier/iter, 4 blocks/CU, XCD-swizzled grid.
// SWAP: m-tile from blockIdx.y (so consecutive ids share the A m-tile).
// LDS layout per buffer: 64 rows x 128B; logical (mrow,g-chunk[16B]) stored at
// row = mrow>>1, slot = ((mrow&1)*4+g) ^ ((mrow>>1)&7)  (conflict-free reads).
// MODE 0: bf16 out[m*ldo+n] = (acc + bias[n]) * scale
// MODE 2: f32  out[m*ldo+n] = acc + bias[m] + resid[m*ldo+n]
// MODE 3: z==0 -> MODE0-style to outp (K proj); z==1 -> V-scatter to outp2
template <int MODE, bool SWAP>
__global__ __launch_bounds__(256, 4) void gemm_nt(
    const u16* __restrict__ A, const u16* __restrict__ Bp,
    const float* __restrict__ bias, void* __restrict__ outp,
    const float* __restrict__ resid, int K, int ldo,
    size_t aStride, size_t bStride, size_t oStride, float scale,
    const u16* __restrict__ Bp2, const float* __restrict__ bias2,
    void* __restrict__ outp2)
{
    __shared__ __align__(16) u16 lA[2][4096];
    __shared__ __align__(16) u16 lB[2][4096];
    const int tid = threadIdx.x;
    const int w = tid >> 6, lane = tid & 63;
    const int g = lane >> 4, r = lane & 15;

    // XCD-aware bijective swizzle of the per-z (x,y) grid (nxy % 8 == 0).
    const int nx = gridDim.x, nxy = nx * gridDim.y;
    const int raw = blockIdx.x + nx * blockIdx.y;
    const int tile = (raw & 7) * (nxy >> 3) + (raw >> 3);
    const int bx = tile % nx, by = tile / nx;
    const int m0 = (SWAP ? by : bx) * 128, n0 = (SWAP ? bx : by) * 128;
    const int z = blockIdx.z;
    A += (size_t)z * aStride;
    const u16* Bsel = Bp;
    if constexpr (MODE == 3) { if (z) Bsel = Bp2; }
    Bsel += (size_t)z * bStride;

    // staging source pre-swizzle (rule #21: linear LDS dest, permuted source)
    const int l8 = lane & 7, lh = lane >> 3;
    const int u_ = l8 ^ lh;                 // slot-at-dest ^ row&7
    const int mro = (lh << 1) + (u_ >> 2);  // row offset within 16-row chunk
    const int kco = (u_ & 3) * 8;           // k offset (elements) within 32
    const int wr = w >> 1, wc = w & 1;
    const int nt = K >> 5;

    f32x4 acc[4][4];
#pragma unroll
    for (int m = 0; m < 4; ++m)
#pragma unroll
        for (int n = 0; n < 4; ++n) acc[m][n] = f32x4{0.f, 0.f, 0.f, 0.f};

#define STAGE_T(t, bi_) {                                                      \
    size_t ko_ = (size_t)((t) * 32 + kco);                                     \
    _Pragma("unroll")                                                          \
    for (int j = 0; j < 2; ++j) {                                              \
        int grow_ = w * 32 + j * 16 + mro;                                     \
        gload16(A + (size_t)(m0 + grow_) * K + ko_,                            \
                &lA[bi_][(w * 16 + j * 8) << 6]);                              \
        gload16(Bsel + (size_t)(n0 + grow_) * K + ko_,                         \
                &lB[bi_][(w * 16 + j * 8) << 6]);                              \
    } }

    STAGE_T(0, 0);
    __syncthreads();

    for (int t = 0; t < nt; ++t) {
        const int cur = t & 1;
        if (t + 1 < nt) STAGE_T(t + 1, cur ^ 1);
        bf16x8 af[4], bf_[4];
#pragma unroll
        for (int m = 0; m < 4; ++m) {
            int row = wr * 32 + m * 8 + (r >> 1);
            int slot = (((r & 1) << 2) + g) ^ ((r >> 1) & 7);
            af[m] = *(const bf16x8*)&lA[cur][(row << 6) + (slot << 3)];
        }
#pragma unroll
        for (int n = 0; n < 4; ++n) {
            int row = wc * 32 + n * 8 + (r >> 1);
            int slot = (((r & 1) << 2) + g) ^ ((r >> 1) & 7);
            bf_[n] = *(const bf16x8*)&lB[cur][(row << 6) + (slot << 3)];
        }
#pragma unroll
        for (int m = 0; m < 4; ++m)
#pragma unroll
            for (int n = 0; n < 4; ++n)
                acc[m][n] = mfma16(af[m], bf_[n], acc[m][n]);
        __syncthreads();
    }
#undef STAGE_T

    if constexpr (MODE == 0) {
        u16* ob = (u16*)outp + (size_t)z * oStride;
#pragma unroll
        for (int n = 0; n < 4; ++n) {
            int gn = n0 + wc * 64 + n * 16 + r;
            float bn = bias[gn] * scale;
#pragma unroll
            for (int m = 0; m < 4; ++m) {
                int gm = m0 + wr * 64 + m * 16 + g * 4;
#pragma unroll
                for (int i = 0; i < 4; ++i)
                    ob[(size_t)(gm + i) * ldo + gn] = f2b(acc[m][n][i] * scale + bn);
            }
        }
    } else if constexpr (MODE == 2) {
        float* of = (float*)outp + (size_t)z * oStride;
        const float* rs = resid + (size_t)z * oStride;
#pragma unroll
        for (int m = 0; m < 4; ++m) {
            int gm = m0 + wr * 64 + m * 16 + g * 4;
#pragma unroll
            for (int i = 0; i < 4; ++i) {
                float bm = bias[gm + i];
#pragma unroll
                for (int n = 0; n < 4; ++n) {
                    int gn = n0 + wc * 64 + n * 16 + r;
                    size_t idx = (size_t)(gm + i) * ldo + gn;
                    of[idx] = acc[m][n][i] + bm + rs[idx];
                }
            }
        }
    } else if constexpr (MODE == 3) {
        if (z == 0) {  // K projection: (b*l, o) bf16
            u16* ob = (u16*)outp;
#pragma unroll
            for (int n = 0; n < 4; ++n) {
                int gn = n0 + wc * 64 + n * 16 + r;
                float bn = bias[gn];
#pragma unroll
                for (int m = 0; m < 4; ++m) {
                    int gm = m0 + wr * 64 + m * 16 + g * 4;
#pragma unroll
                    for (int i = 0; i < 4; ++i)
                        ob[(size_t)(gm + i) * ldo + gn] = f2b(acc[m][n][i] + bn);
                }
            }
        } else {       // V projection scattered to (b,h,e,l) bf16
            u16* ob = (u16*)outp2;
#pragma unroll
            for (int n = 0; n < 4; ++n) {
                int gn = n0 + wc * 64 + n * 16 + r;
                float bn = bias2[gn];
#pragma unroll
                for (int m = 0; m < 4; ++m) {
                    int gm = m0 + wr * 64 + m * 16 + g * 4;
                    int bb = gm >> 8, l = gm & 255;
                    u16x4 pk;
#pragma unroll
                    for (int i = 0; i < 4; ++i) pk[i] = f2b(acc[m][n][i] + bn);
                    *(u16x4*)&ob[((size_t)(bb * 512 + gn)) * 256 + l] = pk;
                }
            }
        }
    }
}

// ---------------------------------------------------------------- attention
// Swapped-QK^T structure: lane holds P[s = m*16 + lane&15][l in regs].
// grid: (S/128, B*NH). block 256 (4 waves, 32 s-rows each). LDS 64KB (K + V).
__global__ __launch_bounds__(256, 2) void attn_kernel(
    const u16* __restrict__ q, const u16* __restrict__ kk,
    const u16* __restrict__ vv, u16* __restrict__ ao)
{
    __shared__ __align__(16) u16 sm[32768];
    const int tid = threadIdx.x;
    const int w = tid >> 6, lane = tid & 63;
    const int g = lane >> 4, r = lane & 15;
    const int bh = blockIdx.y, b = bh >> 3, h = bh & 7;
    const int s0 = blockIdx.x * 128;

    {   // stage K (b,l,h*64+e) rows -> sm[l*64 + swz]
        const u16* kbase = kk + ((size_t)b * L_) * C_ + h * 64;
#pragma unroll
        for (int j = 0; j < 8; ++j) {
            int idx = j * 256 + tid;
            int l = idx >> 3, ch = idx & 7;
            u16x8 val = *(const u16x8*)(kbase + (size_t)l * C_ + ch * 8);
            *(u16x8*)&sm[l * 64 + ((ch ^ (l & 7)) << 3)] = val;
        }
        // stage V (b,h,e,l) rows -> sm[16384 + e*256 + swz]
        const u16* vbase = vv + ((size_t)bh * 64) * 256;
#pragma unroll
        for (int j = 0; j < 8; ++j) {
            int idx = j * 256 + tid;
            int e = idx >> 5, ch = idx & 31;
            u16x8 val = *(const u16x8*)(vbase + (size_t)e * 256 + ch * 8);
            *(u16x8*)&sm[16384 + e * 256 + ((ch ^ (e & 7)) << 3)] = val;
        }
    }

    // Q fragments straight from global (read-once)
    const int sw = s0 + w * 32;
    bf16x8 qf[2][2];
#pragma unroll
    for (int m = 0; m < 2; ++m)
#pragma unroll
        for (int kt = 0; kt < 2; ++kt)
            qf[m][kt] = *(const bf16x8*)(q + ((size_t)(b * S_ + sw + m * 16 + r)) * C_
                                         + h * 64 + kt * 32 + g * 8);
    __syncthreads();

    // QK^T swapped: accs[m][n][i] = P-score[s = m*16 + r][l = n*16 + g*4 + i]
    f32x4 accs[2][16];
#pragma unroll
    for (int m = 0; m < 2; ++m)
#pragma unroll
        for (int n = 0; n < 16; ++n) accs[m][n] = f32x4{0.f, 0.f, 0.f, 0.f};
    __builtin_amdgcn_s_setprio(1);
#pragma unroll
    for (int n = 0; n < 16; ++n) {
#pragma unroll
        for (int kt = 0; kt < 2; ++kt) {
            int c = kt * 4 + g;  // e-chunk index
            bf16x8 kf = *(const bf16x8*)&sm[(n * 16 + r) * 64 + ((c ^ (r & 7)) << 3)];
#pragma unroll
            for (int m = 0; m < 2; ++m) accs[m][n] = mfma16(kf, qf[m][kt], accs[m][n]);
        }
    }
    __builtin_amdgcn_s_setprio(0);

    // softmax: in-lane over 64 values, cross-lane over the 4 lanes sharing r
    float inv[2];
#pragma unroll
    for (int m = 0; m < 2; ++m) {
        float mx = accs[m][0][0];
#pragma unroll
        for (int n = 0; n < 16; ++n)
#pragma unroll
            for (int i = 0; i < 4; ++i) mx = fmaxf(mx, accs[m][n][i]);
        mx = fmaxf(mx, __shfl_xor(mx, 16));
        mx = fmaxf(mx, __shfl_xor(mx, 32));
        float sum = 0.f;
#pragma unroll
        for (int n = 0; n < 16; ++n)
#pragma unroll
            for (int i = 0; i < 4; ++i) {
                float e = __expf(accs[m][n][i] - mx);
                accs[m][n][i] = e; sum += e;
            }
        sum += __shfl_xor(sum, 16);
        sum += __shfl_xor(sum, 32);
        inv[m] = 1.0f / sum;
    }

    // PV: per l-chunk c, repack P in-register into A-fragments, then MFMA
    f32x4 acco[2][4];
#pragma unroll
    for (int m = 0; m < 2; ++m)
#pragma unroll
        for (int n = 0; n < 4; ++n) acco[m][n] = f32x4{0.f, 0.f, 0.f, 0.f};

#pragma unroll
    for (int c = 0; c < 8; ++c) {
        bf16x8 pa[2];
#pragma unroll
        for (int m = 0; m < 2; ++m) {
            u32 x0 = cvtpk(accs[m][2 * c][0] * inv[m], accs[m][2 * c][1] * inv[m]);
            u32 x1 = cvtpk(accs[m][2 * c][2] * inv[m], accs[m][2 * c][3] * inv[m]);
            u32 y0 = cvtpk(accs[m][2 * c + 1][0] * inv[m], accs[m][2 * c + 1][1] * inv[m]);
            u32 y1 = cvtpk(accs[m][2 * c + 1][2] * inv[m], accs[m][2 * c + 1][3] * inv[m]);
            pl32(x0, y0);
            pl32(x1, y1);
            pl16(x0, y0);
            pl16(x1, y1);
            u32x4 pw; pw[0] = x0; pw[1] = x1; pw[2] = y0; pw[3] = y1;
            pa[m] = *(bf16x8*)&pw;
        }
        bf16x8 vf[4];
#pragma unroll
        for (int n = 0; n < 4; ++n) {
            int e = n * 16 + r;
            vf[n] = *(const bf16x8*)&sm[16384 + e * 256 + (((c * 4 + g) ^ (r & 7)) << 3)];
        }
        __builtin_amdgcn_s_setprio(1);
#pragma unroll
        for (int m = 0; m < 2; ++m)
#pragma unroll
            for (int n = 0; n < 4; ++n)
                acco[m][n] = mfma16(pa[m], vf[n], acco[m][n]);
        __builtin_amdgcn_s_setprio(0);
    }

    // write attention output as (b, s, c=h*64+e) bf16
#pragma unroll
    for (int m = 0; m < 2; ++m)
#pragma unroll
        for (int n = 0; n < 4; ++n)
#pragma unroll
            for (int i = 0; i < 4; ++i) {
                int s = sw + m * 16 + g * 4 + i;
                int e = n * 16 + r;
                ao[((size_t)(b * S_ + s)) * C_ + h * 64 + e] = f2b(acco[m][n][i]);
            }
}

// ---------------------------------------------------------------- launch
extern "C" void kernel_launch(void* const* d_in, const int* in_sizes, int n_in,
                              void* d_out, int out_size, void* d_ws, size_t ws_size,
                              hipStream_t stream)
{
    (void)in_sizes; (void)n_in; (void)out_size; (void)ws_size;
    const float* x    = (const float*)d_in[0];
    const float* ctx  = (const float*)d_in[1];
    const float* gn_w = (const float*)d_in[2];
    const float* gn_b = (const float*)d_in[3];
    const float* ln_w = (const float*)d_in[4];
    const float* ln_b = (const float*)d_in[5];
    const float* q_w  = (const float*)d_in[6];
    const float* q_b  = (const float*)d_in[7];
    const float* k_w  = (const float*)d_in[8];
    const float* k_b  = (const float*)d_in[9];
    const float* v_w  = (const float*)d_in[10];
    const float* v_b  = (const float*)d_in[11];
    const float* p_w  = (const float*)d_in[12];
    const float* p_b  = (const float*)d_in[13];
    float* out = (float*)d_out;

    char* ws = (char*)d_ws;
    constexpr size_t WS_WQ   = 0;
    constexpr size_t WS_WK   = WS_WQ + (size_t)512 * 512 * 2;
    constexpr size_t WS_WV   = WS_WK + (size_t)512 * 768 * 2;
    constexpr size_t WS_WP   = WS_WV + (size_t)512 * 768 * 2;
    constexpr size_t WS_PART = WS_WP + (size_t)512 * 512 * 2;
    constexpr size_t WS_STAT = WS_PART + (size_t)16 * 64 * 2 * 4;
    constexpr size_t WS_CTXN = WS_STAT + 256;
    constexpr size_t WS_K    = WS_CTXN + (size_t)512 * 768 * 2;
    constexpr size_t WS_V    = WS_K + (size_t)2 * 8 * 256 * 64 * 2;
    constexpr size_t WS_Q    = WS_V + (size_t)2 * 8 * 256 * 64 * 2;
    constexpr size_t WS_H    = WS_Q + (size_t)2 * 32768 * 512 * 2;

    u16* wq = (u16*)(ws + WS_WQ);
    u16* wk = (u16*)(ws + WS_WK);
    u16* wv = (u16*)(ws + WS_WV);
    u16* wp = (u16*)(ws + WS_WP);
    float* part  = (float*)(ws + WS_PART);
    float* stats = (float*)(ws + WS_STAT);
    u16* ctxn = (u16*)(ws + WS_CTXN);
    u16* kt   = (u16*)(ws + WS_K);
    u16* vt   = (u16*)(ws + WS_V);
    u16* qt   = (u16*)(ws + WS_Q);
    u16* ht   = (u16*)(ws + WS_H);
    u16* ao   = ht;  // h dead after Q-GEMM; reuse for attention output

    const size_t bsc = (size_t)S_ * C_;  // per-batch (s,c)/(c,s) stride

    cvt_w<<<dim3(384, 4), 256, 0, stream>>>(q_w, k_w, v_w, p_w, wq, wk, wv, wp);
    gn_partial<<<dim3(32, 16), 256, 0, stream>>>(x, part);
    gn_final<<<16, 64, 0, stream>>>(part, stats);
    gn_apply<<<dim3(512, 8, 2), 256, 0, stream>>>(x, stats, gn_w, gn_b, ht);
    ln_ctx<<<512, 256, 0, stream>>>(ctx, ln_w, ln_b, ctxn);
    // Q = h . Wq^T (scale folded), out (b,s,o) bf16. SWAP grid: consecutive
    // ids share the ht m-tile -> same XCD after swizzle.
    gemm_nt<0, true><<<dim3(4, 256, 2), 256, 0, stream>>>(
        ht, wq, q_b, qt, nullptr, 512, 512, bsc, 0, bsc, 0.125f,
        nullptr, nullptr, nullptr);
    // K,V = ctxn . W^T in one launch (z selects)
    gemm_nt<3, false><<<dim3(4, 4, 2), 256, 0, stream>>>(
        ctxn, wk, k_b, kt, nullptr, 768, 512, 0, 0, 0, 1.0f,
        wv, v_b, vt);
    attn_kernel<<<dim3(256, 16), 256, 0, stream>>>(qt, kt, vt, ao);
    // out = Wp . ao^T + bias + x (fp32, (b,c,s)). Consecutive ids share the
    // ao n-tile -> same XCD after swizzle.
    gemm_nt<2, false><<<dim3(4, 256, 2), 256, 0, stream>>>(
        wp, ao, p_b, out, x, 512, S_, 0, bsc, bsc, 1.0f,
        nullptr, nullptr, nullptr);
}